// Round 2
// baseline (1193.697 us; speedup 1.0000x reference)
//
#include <hip/hip_runtime.h>

#define CH 64

// =====================================================================
// Shared conv core: 64->64ch, k=4, s=2, p=1, ReLU, input staged in LDS.
// lds[i][pl] holds input position p = 2*m0 - 1 + pl  (pl in [0,130))
// Block = 128 threads: o0 = (tid>>3)*4, mg = tid&7.
// Each thread computes out[o0..o0+3][m0 + mg + 8j], j=0..7.
// =====================================================================
__device__ __forceinline__ void conv_core(
    const float (*lds)[132], const float* __restrict__ w,
    const float* __restrict__ bias, float* __restrict__ out,
    int b, int m0, int Lout, int transpose, int tid)
{
    const int o0 = (tid >> 3) * 4;
    const int mg = tid & 7;
    float acc[4][8];
#pragma unroll
    for (int oo = 0; oo < 4; ++oo) {
        const float bv = bias[o0 + oo];
#pragma unroll
        for (int j = 0; j < 8; ++j) acc[oo][j] = bv;
    }
    for (int i = 0; i < CH; ++i) {
        const float4 w0 = *(const float4*)(w + ((o0 + 0) * CH + i) * 4);
        const float4 w1 = *(const float4*)(w + ((o0 + 1) * CH + i) * 4);
        const float4 w2 = *(const float4*)(w + ((o0 + 2) * CH + i) * 4);
        const float4 w3 = *(const float4*)(w + ((o0 + 3) * CH + i) * 4);
        const float* row = lds[i];
#pragma unroll
        for (int j = 0; j < 8; ++j) {
            const int ml = mg + 8 * j;
            const float2 a = *(const float2*)(row + 2 * ml);
            const float2 c = *(const float2*)(row + 2 * ml + 2);
            acc[0][j] += w0.x * a.x + w0.y * a.y + w0.z * c.x + w0.w * c.y;
            acc[1][j] += w1.x * a.x + w1.y * a.y + w1.z * c.x + w1.w * c.y;
            acc[2][j] += w2.x * a.x + w2.y * a.y + w2.z * c.x + w2.w * c.y;
            acc[3][j] += w3.x * a.x + w3.y * a.y + w3.z * c.x + w3.w * c.y;
        }
    }
    if (!transpose) {
#pragma unroll
        for (int oo = 0; oo < 4; ++oo) {
            float* ob = out + ((size_t)b * CH + o0 + oo) * Lout + m0;
#pragma unroll
            for (int j = 0; j < 8; ++j)
                ob[mg + 8 * j] = fmaxf(acc[oo][j], 0.f);
        }
    } else {
        // z_e layout: [(b*Lout + m)*64 + o]
#pragma unroll
        for (int j = 0; j < 8; ++j) {
            float* ob = out + ((size_t)b * Lout + m0 + mg + 8 * j) * CH + o0;
            float4 v;
            v.x = fmaxf(acc[0][j], 0.f);
            v.y = fmaxf(acc[1][j], 0.f);
            v.z = fmaxf(acc[2][j], 0.f);
            v.w = fmaxf(acc[3][j], 0.f);
            *(float4*)ob = v;
        }
    }
}

// ---------------- generic encoder conv (layers 1..4 of enc_w) ----------------
__global__ __launch_bounds__(128) void k_enc_conv(
    const float* __restrict__ in, const float* __restrict__ w,
    const float* __restrict__ bias, float* __restrict__ out,
    int Lin, int Lout, int transpose)
{
    __shared__ float lds[CH][132];
    const int m0 = blockIdx.x * 64;
    const int b = blockIdx.y;
    const int tid = threadIdx.x;
    const float* inb = in + (size_t)b * CH * Lin;
    const int g0 = 2 * m0 - 1;
    for (int e = tid; e < CH * 132; e += 128) {
        const int i = e / 132;
        const int pl = e - i * 132;
        const int p = g0 + pl;
        lds[i][pl] = (p >= 0 && p < Lin) ? inb[i * Lin + p] : 0.f;
    }
    __syncthreads();
    conv_core(lds, w, bias, out, b, m0, Lout, transpose, tid);
}

// ---------------- fused conv0 (1->64) + conv1 (64->64) ----------------
__global__ __launch_bounds__(128) void k_enc01(
    const float* __restrict__ x, const float* __restrict__ w0,
    const float* __restrict__ b0, const float* __restrict__ w1,
    const float* __restrict__ b1, float* __restrict__ out)
{
    __shared__ float xl[264];
    __shared__ float e0s[CH][132];
    const int m0 = blockIdx.x * 64;
    const int b = blockIdx.y;
    const int tid = threadIdx.x;
    const float* xb = x + (size_t)b * 65536;
    const int q0 = 4 * m0 - 3;
    for (int xi = tid; xi < 264; xi += 128) {
        const int q = q0 + xi;
        xl[xi] = (q >= 0 && q < 65536) ? xb[q] : 0.f;
    }
    __syncthreads();
    {
        const int i = tid >> 1;
        const int half = tid & 1;
        const float4 wv = *(const float4*)(w0 + i * 4);
        const float bv = b0[i];
        const int pl0 = half * 65;
        const int pbase = 2 * m0 - 1;   // e0-space position of pl=0 (e0 length = 32768)
        for (int k = 0; k < 65; ++k) {
            const int pl = pl0 + k;
            const int pe = pbase + pl;
            const float* xp = xl + 2 * pl;
            const float v = wv.x * xp[0] + wv.y * xp[1] + wv.z * xp[2] + wv.w * xp[3] + bv;
            // pe outside [0,32768) is conv1 *padding* -> must be exactly 0
            e0s[i][pl] = (pe >= 0 && pe < 32768) ? fmaxf(v, 0.f) : 0.f;
        }
    }
    __syncthreads();
    conv_core(e0s, w1, b1, out, b, m0, 16384, 0, tid);
}

// ---------------- generic decoder conv-transpose (64->64, relu) ----------------
// y[o,2u]   = b + sum_i w[i,o,1]*x[i,u] + w[i,o,3]*x[i,u-1]
// y[o,2u+1] = b + sum_i w[i,o,2]*x[i,u] + w[i,o,0]*x[i,u+1]
__global__ __launch_bounds__(128) void k_dec_convT(
    const float* __restrict__ in, const float* __restrict__ w,
    const float* __restrict__ bias, float* __restrict__ out, int Lin)
{
    __shared__ float lds[CH][68];   // pl = u - (u0-1), 66 values used
    const int u0 = blockIdx.x * 64;
    const int b = blockIdx.y;
    const int tid = threadIdx.x;
    const float* inb = in + (size_t)b * CH * Lin;
    for (int e = tid; e < CH * 68; e += 128) {
        const int i = e / 68;
        const int pl = e - i * 68;
        const int p = u0 - 1 + pl;
        lds[i][pl] = (pl < 66 && p >= 0 && p < Lin) ? inb[i * Lin + p] : 0.f;
    }
    __syncthreads();
    const int o0 = (tid >> 3) * 4;
    const int ug = tid & 7;
    float accE[4][8], accO[4][8];
#pragma unroll
    for (int oo = 0; oo < 4; ++oo) {
        const float bv = bias[o0 + oo];
#pragma unroll
        for (int j = 0; j < 8; ++j) { accE[oo][j] = bv; accO[oo][j] = bv; }
    }
    for (int i = 0; i < CH; ++i) {
        const float4 w0 = *(const float4*)(w + (i * CH + o0 + 0) * 4);
        const float4 w1 = *(const float4*)(w + (i * CH + o0 + 1) * 4);
        const float4 w2 = *(const float4*)(w + (i * CH + o0 + 2) * 4);
        const float4 w3 = *(const float4*)(w + (i * CH + o0 + 3) * 4);
        const float* row = lds[i];
#pragma unroll
        for (int j = 0; j < 8; ++j) {
            const int ul = ug + 8 * j;
            const float xa = row[ul];       // x[u-1]
            const float xb_ = row[ul + 1];  // x[u]
            const float xc = row[ul + 2];   // x[u+1]
            accE[0][j] += w0.y * xb_ + w0.w * xa;
            accO[0][j] += w0.z * xb_ + w0.x * xc;
            accE[1][j] += w1.y * xb_ + w1.w * xa;
            accO[1][j] += w1.z * xb_ + w1.x * xc;
            accE[2][j] += w2.y * xb_ + w2.w * xa;
            accO[2][j] += w2.z * xb_ + w2.x * xc;
            accE[3][j] += w3.y * xb_ + w3.w * xa;
            accO[3][j] += w3.z * xb_ + w3.x * xc;
        }
    }
    const int Lout = 2 * Lin;
#pragma unroll
    for (int oo = 0; oo < 4; ++oo) {
        float* ob = out + ((size_t)b * CH + o0 + oo) * Lout;
#pragma unroll
        for (int j = 0; j < 8; ++j) {
            const int n = 2 * (u0 + ug + 8 * j);
            float2 v;
            v.x = fmaxf(accE[oo][j], 0.f);
            v.y = fmaxf(accO[oo][j], 0.f);
            *(float2*)(ob + n) = v;
        }
    }
}

// ---------------- VQ: argmin_c |z-c|^2, write ids + gathered g ----------------
__global__ __launch_bounds__(256) void k_vq(
    const float* __restrict__ z, const float* __restrict__ cb,
    float* __restrict__ idsf, float* __restrict__ g)
{
    __shared__ float zl[64][68];
    __shared__ float cl[64][68];
    __shared__ float c2l[64];
    __shared__ float rval[64][16];
    __shared__ int ridx[64][16];
    __shared__ int widx[64];
    const int t0 = blockIdx.x * 64;
    const int tid = threadIdx.x;
    for (int e = tid; e < 64 * 64; e += 256) {
        const int tok = e >> 6, d = e & 63;
        zl[tok][d] = z[(size_t)(t0 + tok) * 64 + d];
    }
    const int tg = tid >> 4, cg = tid & 15;
    float best[4];
    int bidx[4];
#pragma unroll
    for (int tt = 0; tt < 4; ++tt) { best[tt] = 3.0e38f; bidx[tt] = 0; }
    for (int chk = 0; chk < 16; ++chk) {
        __syncthreads();
        for (int e = tid; e < 64 * 64; e += 256) {
            const int c = e >> 6, d = e & 63;
            cl[c][d] = cb[(size_t)(chk * 64 + c) * 64 + d];
        }
        __syncthreads();
        if (tid < 64) {
            float s = 0.f;
            for (int d = 0; d < 64; ++d) { const float v = cl[tid][d]; s += v * v; }
            c2l[tid] = s;
        }
        __syncthreads();
        float acc[4][4];
#pragma unroll
        for (int a = 0; a < 4; ++a)
#pragma unroll
            for (int c = 0; c < 4; ++c) acc[a][c] = 0.f;
        for (int d4 = 0; d4 < 16; ++d4) {
            float4 zv[4], cv[4];
#pragma unroll
            for (int tt = 0; tt < 4; ++tt) zv[tt] = *(const float4*)&zl[tg * 4 + tt][d4 * 4];
#pragma unroll
            for (int cc = 0; cc < 4; ++cc) cv[cc] = *(const float4*)&cl[cg * 4 + cc][d4 * 4];
#pragma unroll
            for (int tt = 0; tt < 4; ++tt)
#pragma unroll
                for (int cc = 0; cc < 4; ++cc)
                    acc[tt][cc] += zv[tt].x * cv[cc].x + zv[tt].y * cv[cc].y
                                 + zv[tt].z * cv[cc].z + zv[tt].w * cv[cc].w;
        }
#pragma unroll
        for (int cc = 0; cc < 4; ++cc) {
            const int code = chk * 64 + cg * 4 + cc;
            const float c2v = c2l[cg * 4 + cc];
#pragma unroll
            for (int tt = 0; tt < 4; ++tt) {
                const float s = c2v - 2.f * acc[tt][cc];
                if (s < best[tt]) { best[tt] = s; bidx[tt] = code; }
            }
        }
    }
#pragma unroll
    for (int tt = 0; tt < 4; ++tt) {
        rval[tg * 4 + tt][cg] = best[tt];
        ridx[tg * 4 + tt][cg] = bidx[tt];
    }
    __syncthreads();
    if (tid < 64) {
        float bv = rval[tid][0];
        int bi = ridx[tid][0];
        for (int k = 1; k < 16; ++k) {
            const float v = rval[tid][k];
            const int ix = ridx[tid][k];
            if (v < bv || (v == bv && ix < bi)) { bv = v; bi = ix; }
        }
        widx[tid] = bi;
        idsf[t0 + tid] = (float)bi;
    }
    __syncthreads();
    const int bb = t0 >> 10;
    const int mb = t0 & 1023;
    for (int e = tid; e < 64 * 64; e += 256) {
        const int tok = e & 63;
        const int d = e >> 6;
        g[((size_t)bb * CH + d) * 1024 + mb + tok] = cb[(size_t)widx[tok] * 64 + d];
    }
}

// ---------------- fused dec4 (relu, 64->64) + last convT (64->1, no relu) ----
__global__ __launch_bounds__(256) void k_dec_last(
    const float* __restrict__ in, const float* __restrict__ w4,
    const float* __restrict__ b4, const float* __restrict__ wl,
    const float* __restrict__ blp, float* __restrict__ y)
{
    __shared__ float d3l[CH][70];    // d3, pl = m - mbase, 68 values
    __shared__ float d4l[CH][134];   // d4, pl = u - (v0-2), 132 values
    const int n0 = blockIdx.x * 256;
    const int b = blockIdx.y;
    const int tid = threadIdx.x;
    const int v0 = n0 >> 1;
    const int mbase = (v0 >> 1) - 2;
    const float* inb = in + (size_t)b * CH * 16384;
    for (int e = tid; e < CH * 68; e += 256) {
        const int i = e / 68;
        const int pl = e - i * 68;
        const int p = mbase + pl;
        d3l[i][pl] = (p >= 0 && p < 16384) ? inb[i * 16384 + p] : 0.f;
    }
    __syncthreads();
    {
        const int o = tid >> 2;
        const int l4 = tid & 3;
        const int ubase = v0 - 2 + l4;
        const int odd = l4 & 1;
        float acc[33];
        const float bv = b4[o];
#pragma unroll
        for (int k = 0; k < 33; ++k) acc[k] = bv;
        for (int i = 0; i < CH; ++i) {
            const float4 wv = *(const float4*)(w4 + (i * CH + o) * 4);
            const float wA = odd ? wv.z : wv.y;
            const float wB = odd ? wv.x : wv.w;
            const float* row = d3l[i];
#pragma unroll
            for (int k = 0; k < 33; ++k) {
                const int u = ubase + 4 * k;
                const int s = u >> 1;
                const int plA = s - mbase;
                const int plB = plA + (odd ? 1 : -1);
                acc[k] += wA * row[plA] + wB * row[plB];
            }
        }
#pragma unroll
        for (int k = 0; k < 33; ++k) {
            const int u = ubase + 4 * k;
            const float v = (u >= 0 && u < 32768) ? fmaxf(acc[k], 0.f) : 0.f;
            d4l[o][l4 + 4 * k] = v;
        }
    }
    __syncthreads();
    {
        const int n = n0 + tid;
        const int v = n >> 1;
        const int odd = n & 1;
        const int plA = v - v0 + 2;
        const int plB = plA + (odd ? 1 : -1);
        float acc = blp[0];
        for (int i = 0; i < CH; ++i) {
            const float4 wv = *(const float4*)(wl + i * 4);
            const float wA = odd ? wv.z : wv.y;
            const float wB = odd ? wv.x : wv.w;
            acc += wA * d4l[i][plA] + wB * d4l[i][plB];
        }
        y[(size_t)b * 65536 + n] = acc;
    }
}

extern "C" void kernel_launch(void* const* d_in, const int* in_sizes, int n_in,
                              void* d_out, int out_size, void* d_ws, size_t ws_size,
                              hipStream_t stream) {
    const float* x      = (const float*)d_in[0];
    const float* enc_w0 = (const float*)d_in[1];
    const float* enc_w  = (const float*)d_in[2];   // (5,64,64,4)
    const float* enc_b  = (const float*)d_in[3];   // (6,64)
    const float* cb     = (const float*)d_in[4];   // (1024,64)
    const float* dec_w  = (const float*)d_in[5];   // (5,64,64,4) [in][out][k]
    const float* dec_wl = (const float*)d_in[6];   // (64,1,4)
    const float* dec_b  = (const float*)d_in[7];   // (5,64)
    const float* dec_bl = (const float*)d_in[8];   // (1,)
    float* y    = (float*)d_out;                   // (16,1,65536)
    float* z_e  = y + 1048576;                     // (16384,64)
    float* idsf = y + 2097152;                     // (16384,) stored as float

    // workspace overlay: A = 67.1MB (16.7M floats), B = 33.6MB (8.4M floats)
    float* A  = (float*)d_ws;
    float* Bf = A + 16777216;

    const int WSTRIDE = 64 * 64 * 4;

    // encoder
    k_enc01<<<dim3(256, 16), 128, 0, stream>>>(x, enc_w0, enc_b, enc_w, enc_b + 64, A);
    k_enc_conv<<<dim3(128, 16), 128, 0, stream>>>(A,  enc_w + 1 * WSTRIDE, enc_b + 2 * 64, Bf, 16384, 8192, 0);
    k_enc_conv<<<dim3(64, 16),  128, 0, stream>>>(Bf, enc_w + 2 * WSTRIDE, enc_b + 3 * 64, A,  8192,  4096, 0);
    k_enc_conv<<<dim3(32, 16),  128, 0, stream>>>(A,  enc_w + 3 * WSTRIDE, enc_b + 4 * 64, Bf, 4096,  2048, 0);
    k_enc_conv<<<dim3(16, 16),  128, 0, stream>>>(Bf, enc_w + 4 * WSTRIDE, enc_b + 5 * 64, z_e, 2048, 1024, 1);
    // vector quantize
    k_vq<<<256, 256, 0, stream>>>(z_e, cb, idsf, A);
    // decoder
    k_dec_convT<<<dim3(16, 16),  128, 0, stream>>>(A,  dec_w + 0 * WSTRIDE, dec_b + 0 * 64, Bf, 1024);
    k_dec_convT<<<dim3(32, 16),  128, 0, stream>>>(Bf, dec_w + 1 * WSTRIDE, dec_b + 1 * 64, A,  2048);
    k_dec_convT<<<dim3(64, 16),  128, 0, stream>>>(A,  dec_w + 2 * WSTRIDE, dec_b + 2 * 64, Bf, 4096);
    k_dec_convT<<<dim3(128, 16), 128, 0, stream>>>(Bf, dec_w + 3 * WSTRIDE, dec_b + 3 * 64, A,  8192);
    k_dec_last<<<dim3(256, 16), 256, 0, stream>>>(A, dec_w + 4 * WSTRIDE, dec_b + 4 * 64, dec_wl, dec_bl, y);
}

// Round 3
// 1060.968 us; speedup vs baseline: 1.1251x; 1.1251x over previous
//
#include <hip/hip_runtime.h>

#define CH 64

// =====================================================================
// Shared conv core: 64->64ch, k=4, s=2, p=1, ReLU, input staged in LDS.
// lds[i][pl] holds input position p = 2*m0 - 1 + pl  (pl in [0,130))
// Block = 128 threads: o0 = (tid>>3)*4, mg = tid&7.
// Each thread computes out[o0..o0+3][m0 + mg + 8j], j=0..7.
// =====================================================================
__device__ __forceinline__ void conv_core(
    const float (*lds)[132], const float* __restrict__ w,
    const float* __restrict__ bias, float* __restrict__ out,
    int b, int m0, int Lout, int transpose, int tid)
{
    const int o0 = (tid >> 3) * 4;
    const int mg = tid & 7;
    float acc[4][8];
#pragma unroll
    for (int oo = 0; oo < 4; ++oo) {
        const float bv = bias[o0 + oo];
#pragma unroll
        for (int j = 0; j < 8; ++j) acc[oo][j] = bv;
    }
    for (int i = 0; i < CH; ++i) {
        const float4 w0 = *(const float4*)(w + ((o0 + 0) * CH + i) * 4);
        const float4 w1 = *(const float4*)(w + ((o0 + 1) * CH + i) * 4);
        const float4 w2 = *(const float4*)(w + ((o0 + 2) * CH + i) * 4);
        const float4 w3 = *(const float4*)(w + ((o0 + 3) * CH + i) * 4);
        const float* row = lds[i];
#pragma unroll
        for (int j = 0; j < 8; ++j) {
            const int ml = mg + 8 * j;
            const float2 a = *(const float2*)(row + 2 * ml);
            const float2 c = *(const float2*)(row + 2 * ml + 2);
            acc[0][j] += w0.x * a.x + w0.y * a.y + w0.z * c.x + w0.w * c.y;
            acc[1][j] += w1.x * a.x + w1.y * a.y + w1.z * c.x + w1.w * c.y;
            acc[2][j] += w2.x * a.x + w2.y * a.y + w2.z * c.x + w2.w * c.y;
            acc[3][j] += w3.x * a.x + w3.y * a.y + w3.z * c.x + w3.w * c.y;
        }
    }
    if (!transpose) {
#pragma unroll
        for (int oo = 0; oo < 4; ++oo) {
            float* ob = out + ((size_t)b * CH + o0 + oo) * Lout + m0;
#pragma unroll
            for (int j = 0; j < 8; ++j)
                ob[mg + 8 * j] = fmaxf(acc[oo][j], 0.f);
        }
    } else {
        // z_e layout: [(b*Lout + m)*64 + o]
#pragma unroll
        for (int j = 0; j < 8; ++j) {
            float* ob = out + ((size_t)b * Lout + m0 + mg + 8 * j) * CH + o0;
            float4 v;
            v.x = fmaxf(acc[0][j], 0.f);
            v.y = fmaxf(acc[1][j], 0.f);
            v.z = fmaxf(acc[2][j], 0.f);
            v.w = fmaxf(acc[3][j], 0.f);
            *(float4*)ob = v;
        }
    }
}

// ---------------- generic encoder conv (layers 1..4 of enc_w) ----------------
__global__ __launch_bounds__(128) void k_enc_conv(
    const float* __restrict__ in, const float* __restrict__ w,
    const float* __restrict__ bias, float* __restrict__ out,
    int Lin, int Lout, int transpose)
{
    __shared__ float lds[CH][132];
    const int m0 = blockIdx.x * 64;
    const int b = blockIdx.y;
    const int tid = threadIdx.x;
    const float* inb = in + (size_t)b * CH * Lin;
    const int g0 = 2 * m0 - 1;
    for (int e = tid; e < CH * 132; e += 128) {
        const int i = e / 132;
        const int pl = e - i * 132;
        const int p = g0 + pl;
        lds[i][pl] = (p >= 0 && p < Lin) ? inb[i * Lin + p] : 0.f;
    }
    __syncthreads();
    conv_core(lds, w, bias, out, b, m0, Lout, transpose, tid);
}

// ---------------- fused conv0 (1->64) + conv1 (64->64) ----------------
__global__ __launch_bounds__(128) void k_enc01(
    const float* __restrict__ x, const float* __restrict__ w0,
    const float* __restrict__ b0, const float* __restrict__ w1,
    const float* __restrict__ b1, float* __restrict__ out)
{
    __shared__ float xl[264];
    __shared__ float e0s[CH][132];
    const int m0 = blockIdx.x * 64;
    const int b = blockIdx.y;
    const int tid = threadIdx.x;
    const float* xb = x + (size_t)b * 65536;
    const int q0 = 4 * m0 - 3;
    for (int xi = tid; xi < 264; xi += 128) {
        const int q = q0 + xi;
        xl[xi] = (q >= 0 && q < 65536) ? xb[q] : 0.f;
    }
    __syncthreads();
    {
        const int i = tid >> 1;
        const int half = tid & 1;
        const float4 wv = *(const float4*)(w0 + i * 4);
        const float bv = b0[i];
        const int pl0 = half * 65;
        const int pbase = 2 * m0 - 1;   // e0-space position of pl=0 (e0 length = 32768)
        for (int k = 0; k < 65; ++k) {
            const int pl = pl0 + k;
            const int pe = pbase + pl;
            const float* xp = xl + 2 * pl;
            const float v = wv.x * xp[0] + wv.y * xp[1] + wv.z * xp[2] + wv.w * xp[3] + bv;
            // pe outside [0,32768) is conv1 *padding* -> must be exactly 0
            e0s[i][pl] = (pe >= 0 && pe < 32768) ? fmaxf(v, 0.f) : 0.f;
        }
    }
    __syncthreads();
    conv_core(e0s, w1, b1, out, b, m0, 16384, 0, tid);
}

// ---------------- generic decoder conv-transpose (64->64, relu) ----------------
// y[o,2u]   = b + sum_i w[i,o,1]*x[i,u] + w[i,o,3]*x[i,u-1]
// y[o,2u+1] = b + sum_i w[i,o,2]*x[i,u] + w[i,o,0]*x[i,u+1]
__global__ __launch_bounds__(128) void k_dec_convT(
    const float* __restrict__ in, const float* __restrict__ w,
    const float* __restrict__ bias, float* __restrict__ out, int Lin)
{
    __shared__ float lds[CH][68];   // pl = u - (u0-1), 66 values used
    const int u0 = blockIdx.x * 64;
    const int b = blockIdx.y;
    const int tid = threadIdx.x;
    const float* inb = in + (size_t)b * CH * Lin;
    for (int e = tid; e < CH * 68; e += 128) {
        const int i = e / 68;
        const int pl = e - i * 68;
        const int p = u0 - 1 + pl;
        lds[i][pl] = (pl < 66 && p >= 0 && p < Lin) ? inb[i * Lin + p] : 0.f;
    }
    __syncthreads();
    const int o0 = (tid >> 3) * 4;
    const int ug = tid & 7;
    float accE[4][8], accO[4][8];
#pragma unroll
    for (int oo = 0; oo < 4; ++oo) {
        const float bv = bias[o0 + oo];
#pragma unroll
        for (int j = 0; j < 8; ++j) { accE[oo][j] = bv; accO[oo][j] = bv; }
    }
    for (int i = 0; i < CH; ++i) {
        const float4 w0 = *(const float4*)(w + (i * CH + o0 + 0) * 4);
        const float4 w1 = *(const float4*)(w + (i * CH + o0 + 1) * 4);
        const float4 w2 = *(const float4*)(w + (i * CH + o0 + 2) * 4);
        const float4 w3 = *(const float4*)(w + (i * CH + o0 + 3) * 4);
        const float* row = lds[i];
#pragma unroll
        for (int j = 0; j < 8; ++j) {
            const int ul = ug + 8 * j;
            const float xa = row[ul];       // x[u-1]
            const float xb_ = row[ul + 1];  // x[u]
            const float xc = row[ul + 2];   // x[u+1]
            accE[0][j] += w0.y * xb_ + w0.w * xa;
            accO[0][j] += w0.z * xb_ + w0.x * xc;
            accE[1][j] += w1.y * xb_ + w1.w * xa;
            accO[1][j] += w1.z * xb_ + w1.x * xc;
            accE[2][j] += w2.y * xb_ + w2.w * xa;
            accO[2][j] += w2.z * xb_ + w2.x * xc;
            accE[3][j] += w3.y * xb_ + w3.w * xa;
            accO[3][j] += w3.z * xb_ + w3.x * xc;
        }
    }
    const int Lout = 2 * Lin;
#pragma unroll
    for (int oo = 0; oo < 4; ++oo) {
        float* ob = out + ((size_t)b * CH + o0 + oo) * Lout;
#pragma unroll
        for (int j = 0; j < 8; ++j) {
            const int n = 2 * (u0 + ug + 8 * j);
            float2 v;
            v.x = fmaxf(accE[oo][j], 0.f);
            v.y = fmaxf(accO[oo][j], 0.f);
            *(float2*)(ob + n) = v;
        }
    }
}

// ---------------- VQ: argmin_c |z-c|^2, write ids + gathered g ----------------
__global__ __launch_bounds__(256) void k_vq(
    const float* __restrict__ z, const float* __restrict__ cb,
    float* __restrict__ idsf, float* __restrict__ g)
{
    __shared__ float zl[64][68];
    __shared__ float cl[64][68];
    __shared__ float c2l[64];
    __shared__ float rval[64][16];
    __shared__ int ridx[64][16];
    __shared__ int widx[64];
    const int t0 = blockIdx.x * 64;
    const int tid = threadIdx.x;
    for (int e = tid; e < 64 * 64; e += 256) {
        const int tok = e >> 6, d = e & 63;
        zl[tok][d] = z[(size_t)(t0 + tok) * 64 + d];
    }
    const int tg = tid >> 4, cg = tid & 15;
    float best[4];
    int bidx[4];
#pragma unroll
    for (int tt = 0; tt < 4; ++tt) { best[tt] = 3.0e38f; bidx[tt] = 0; }
    for (int chk = 0; chk < 16; ++chk) {
        __syncthreads();
        for (int e = tid; e < 64 * 64; e += 256) {
            const int c = e >> 6, d = e & 63;
            cl[c][d] = cb[(size_t)(chk * 64 + c) * 64 + d];
        }
        __syncthreads();
        if (tid < 64) {
            float s = 0.f;
            for (int d = 0; d < 64; ++d) { const float v = cl[tid][d]; s += v * v; }
            c2l[tid] = s;
        }
        __syncthreads();
        float acc[4][4];
#pragma unroll
        for (int a = 0; a < 4; ++a)
#pragma unroll
            for (int c = 0; c < 4; ++c) acc[a][c] = 0.f;
        for (int d4 = 0; d4 < 16; ++d4) {
            float4 zv[4], cv[4];
#pragma unroll
            for (int tt = 0; tt < 4; ++tt) zv[tt] = *(const float4*)&zl[tg * 4 + tt][d4 * 4];
#pragma unroll
            for (int cc = 0; cc < 4; ++cc) cv[cc] = *(const float4*)&cl[cg * 4 + cc][d4 * 4];
#pragma unroll
            for (int tt = 0; tt < 4; ++tt)
#pragma unroll
                for (int cc = 0; cc < 4; ++cc)
                    acc[tt][cc] += zv[tt].x * cv[cc].x + zv[tt].y * cv[cc].y
                                 + zv[tt].z * cv[cc].z + zv[tt].w * cv[cc].w;
        }
#pragma unroll
        for (int cc = 0; cc < 4; ++cc) {
            const int code = chk * 64 + cg * 4 + cc;
            const float c2v = c2l[cg * 4 + cc];
#pragma unroll
            for (int tt = 0; tt < 4; ++tt) {
                const float s = c2v - 2.f * acc[tt][cc];
                if (s < best[tt]) { best[tt] = s; bidx[tt] = code; }
            }
        }
    }
#pragma unroll
    for (int tt = 0; tt < 4; ++tt) {
        rval[tg * 4 + tt][cg] = best[tt];
        ridx[tg * 4 + tt][cg] = bidx[tt];
    }
    __syncthreads();
    if (tid < 64) {
        float bv = rval[tid][0];
        int bi = ridx[tid][0];
        for (int k = 1; k < 16; ++k) {
            const float v = rval[tid][k];
            const int ix = ridx[tid][k];
            if (v < bv || (v == bv && ix < bi)) { bv = v; bi = ix; }
        }
        widx[tid] = bi;
        idsf[t0 + tid] = (float)bi;
    }
    __syncthreads();
    const int bb = t0 >> 10;
    const int mb = t0 & 1023;
    for (int e = tid; e < 64 * 64; e += 256) {
        const int tok = e & 63;
        const int d = e >> 6;
        g[((size_t)bb * CH + d) * 1024 + mb + tok] = cb[(size_t)widx[tok] * 64 + d];
    }
}

// ---------------- fused dec4 (relu, 64->64) + last convT (64->1, no relu) ----
// Stage B restructured: 4 out-ch x ~4 m-columns per thread so each LDS read
// of d3 feeds 16 FMAs (was 1). LDS-read instr count drops ~5x.
__global__ __launch_bounds__(256) void k_dec_last(
    const float* __restrict__ in, const float* __restrict__ w4,
    const float* __restrict__ b4, const float* __restrict__ wl,
    const float* __restrict__ blp, float* __restrict__ y)
{
    __shared__ float d3l[CH][68];    // d3, ml = m - mbase, 68 values
    __shared__ float d4l[CH][132];   // d4, pl = u - (v0-2), 132 values
    const int n0 = blockIdx.x * 256;
    const int b = blockIdx.y;
    const int tid = threadIdx.x;
    const int v0 = n0 >> 1;
    const int mbase = (v0 >> 1) - 2;
    const float* inb = in + (size_t)b * CH * 16384;
    for (int e = tid; e < CH * 68; e += 256) {
        const int i = e / 68;
        const int pl = e - i * 68;
        const int p = mbase + pl;
        d3l[i][pl] = (p >= 0 && p < 16384) ? inb[i * 16384 + p] : 0.f;
    }
    __syncthreads();
    {
        // d4[o][2m]   = relu(b + sum_i w.y*d3[i][m] + w.w*d3[i][m-1])
        // d4[o][2m+1] = relu(b + sum_i w.z*d3[i][m] + w.x*d3[i][m+1])
        // m = (v0/2 - 1) + m_local, m_local = mg + 16*c in [0,66)
        // d3l index: ml = m_local (m-1), m_local+1 (m), m_local+2 (m+1)
        const int o0 = (tid >> 4) * 4;
        const int mg = tid & 15;
        float accE[4][5], accO[4][5];
#pragma unroll
        for (int k = 0; k < 4; ++k) {
            const float bv = b4[o0 + k];
#pragma unroll
            for (int c = 0; c < 5; ++c) { accE[k][c] = bv; accO[k][c] = bv; }
        }
        for (int i = 0; i < CH; ++i) {
            const float4 w0 = *(const float4*)(w4 + (i * CH + o0 + 0) * 4);
            const float4 w1 = *(const float4*)(w4 + (i * CH + o0 + 1) * 4);
            const float4 w2 = *(const float4*)(w4 + (i * CH + o0 + 2) * 4);
            const float4 w3 = *(const float4*)(w4 + (i * CH + o0 + 3) * 4);
            const float* row = d3l[i];
#pragma unroll
            for (int c = 0; c < 4; ++c) {
                const int ml = mg + 16 * c;
                const float xm1 = row[ml];
                const float x0  = row[ml + 1];
                const float xp1 = row[ml + 2];
                accE[0][c] += w0.y * x0 + w0.w * xm1;
                accO[0][c] += w0.z * x0 + w0.x * xp1;
                accE[1][c] += w1.y * x0 + w1.w * xm1;
                accO[1][c] += w1.z * x0 + w1.x * xp1;
                accE[2][c] += w2.y * x0 + w2.w * xm1;
                accO[2][c] += w2.z * x0 + w2.x * xp1;
                accE[3][c] += w3.y * x0 + w3.w * xm1;
                accO[3][c] += w3.z * x0 + w3.x * xp1;
            }
            if (mg < 2) {
                const int ml = mg + 64;
                const float xm1 = row[ml];
                const float x0  = row[ml + 1];
                const float xp1 = row[ml + 2];
                accE[0][4] += w0.y * x0 + w0.w * xm1;
                accO[0][4] += w0.z * x0 + w0.x * xp1;
                accE[1][4] += w1.y * x0 + w1.w * xm1;
                accO[1][4] += w1.z * x0 + w1.x * xp1;
                accE[2][4] += w2.y * x0 + w2.w * xm1;
                accO[2][4] += w2.z * x0 + w2.x * xp1;
                accE[3][4] += w3.y * x0 + w3.w * xm1;
                accO[3][4] += w3.z * x0 + w3.x * xp1;
            }
        }
#pragma unroll
        for (int k = 0; k < 4; ++k) {
#pragma unroll
            for (int c = 0; c < 5; ++c) {
                const int m_local = mg + 16 * c;
                if (m_local < 66) {
                    const int plE = 2 * m_local;
                    const int uE = v0 - 2 + plE;
                    const int uO = uE + 1;
                    float2 v;
                    v.x = (uE >= 0 && uE < 32768) ? fmaxf(accE[k][c], 0.f) : 0.f;
                    v.y = (uO >= 0 && uO < 32768) ? fmaxf(accO[k][c], 0.f) : 0.f;
                    *(float2*)&d4l[o0 + k][plE] = v;
                }
            }
        }
    }
    __syncthreads();
    {
        const int n = n0 + tid;
        const int v = n >> 1;
        const int odd = n & 1;
        const int plA = v - v0 + 2;
        const int plB = plA + (odd ? 1 : -1);
        float acc = blp[0];
        for (int i = 0; i < CH; ++i) {
            const float4 wv = *(const float4*)(wl + i * 4);
            const float wA = odd ? wv.z : wv.y;
            const float wB = odd ? wv.x : wv.w;
            acc += wA * d4l[i][plA] + wB * d4l[i][plB];
        }
        y[(size_t)b * 65536 + n] = acc;
    }
}

extern "C" void kernel_launch(void* const* d_in, const int* in_sizes, int n_in,
                              void* d_out, int out_size, void* d_ws, size_t ws_size,
                              hipStream_t stream) {
    const float* x      = (const float*)d_in[0];
    const float* enc_w0 = (const float*)d_in[1];
    const float* enc_w  = (const float*)d_in[2];   // (5,64,64,4)
    const float* enc_b  = (const float*)d_in[3];   // (6,64)
    const float* cb     = (const float*)d_in[4];   // (1024,64)
    const float* dec_w  = (const float*)d_in[5];   // (5,64,64,4) [in][out][k]
    const float* dec_wl = (const float*)d_in[6];   // (64,1,4)
    const float* dec_b  = (const float*)d_in[7];   // (5,64)
    const float* dec_bl = (const float*)d_in[8];   // (1,)
    float* y    = (float*)d_out;                   // (16,1,65536)
    float* z_e  = y + 1048576;                     // (16384,64)
    float* idsf = y + 2097152;                     // (16384,) stored as float

    // workspace overlay: A = 67.1MB (16.7M floats), B = 33.6MB (8.4M floats)
    float* A  = (float*)d_ws;
    float* Bf = A + 16777216;

    const int WSTRIDE = 64 * 64 * 4;

    // encoder
    k_enc01<<<dim3(256, 16), 128, 0, stream>>>(x, enc_w0, enc_b, enc_w, enc_b + 64, A);
    k_enc_conv<<<dim3(128, 16), 128, 0, stream>>>(A,  enc_w + 1 * WSTRIDE, enc_b + 2 * 64, Bf, 16384, 8192, 0);
    k_enc_conv<<<dim3(64, 16),  128, 0, stream>>>(Bf, enc_w + 2 * WSTRIDE, enc_b + 3 * 64, A,  8192,  4096, 0);
    k_enc_conv<<<dim3(32, 16),  128, 0, stream>>>(A,  enc_w + 3 * WSTRIDE, enc_b + 4 * 64, Bf, 4096,  2048, 0);
    k_enc_conv<<<dim3(16, 16),  128, 0, stream>>>(Bf, enc_w + 4 * WSTRIDE, enc_b + 5 * 64, z_e, 2048, 1024, 1);
    // vector quantize
    k_vq<<<256, 256, 0, stream>>>(z_e, cb, idsf, A);
    // decoder
    k_dec_convT<<<dim3(16, 16),  128, 0, stream>>>(A,  dec_w + 0 * WSTRIDE, dec_b + 0 * 64, Bf, 1024);
    k_dec_convT<<<dim3(32, 16),  128, 0, stream>>>(Bf, dec_w + 1 * WSTRIDE, dec_b + 1 * 64, A,  2048);
    k_dec_convT<<<dim3(64, 16),  128, 0, stream>>>(A,  dec_w + 2 * WSTRIDE, dec_b + 2 * 64, Bf, 4096);
    k_dec_convT<<<dim3(128, 16), 128, 0, stream>>>(Bf, dec_w + 3 * WSTRIDE, dec_b + 3 * 64, A,  8192);
    k_dec_last<<<dim3(256, 16), 256, 0, stream>>>(A, dec_w + 4 * WSTRIDE, dec_b + 4 * 64, dec_wl, dec_bl, y);
}

// Round 4
// 851.105 us; speedup vs baseline: 1.4025x; 1.2466x over previous
//
#include <hip/hip_runtime.h>

#define CH 64

typedef short s16x8 __attribute__((ext_vector_type(8)));
typedef float f32x4 __attribute__((ext_vector_type(4)));

static __device__ __forceinline__ ushort f2bf(float f) {
    union { float f; uint u; } v; v.f = f;
    const uint r = (v.u + 0x7FFFu + ((v.u >> 16) & 1u)) >> 16;
    return (ushort)r;
}

// =====================================================================
// ENCODER (fp32, unchanged from round 3)
// =====================================================================
__device__ __forceinline__ void conv_core(
    const float (*lds)[132], const float* __restrict__ w,
    const float* __restrict__ bias, float* __restrict__ out,
    int b, int m0, int Lout, int transpose, int tid)
{
    const int o0 = (tid >> 3) * 4;
    const int mg = tid & 7;
    float acc[4][8];
#pragma unroll
    for (int oo = 0; oo < 4; ++oo) {
        const float bv = bias[o0 + oo];
#pragma unroll
        for (int j = 0; j < 8; ++j) acc[oo][j] = bv;
    }
    for (int i = 0; i < CH; ++i) {
        const float4 w0 = *(const float4*)(w + ((o0 + 0) * CH + i) * 4);
        const float4 w1 = *(const float4*)(w + ((o0 + 1) * CH + i) * 4);
        const float4 w2 = *(const float4*)(w + ((o0 + 2) * CH + i) * 4);
        const float4 w3 = *(const float4*)(w + ((o0 + 3) * CH + i) * 4);
        const float* row = lds[i];
#pragma unroll
        for (int j = 0; j < 8; ++j) {
            const int ml = mg + 8 * j;
            const float2 a = *(const float2*)(row + 2 * ml);
            const float2 c = *(const float2*)(row + 2 * ml + 2);
            acc[0][j] += w0.x * a.x + w0.y * a.y + w0.z * c.x + w0.w * c.y;
            acc[1][j] += w1.x * a.x + w1.y * a.y + w1.z * c.x + w1.w * c.y;
            acc[2][j] += w2.x * a.x + w2.y * a.y + w2.z * c.x + w2.w * c.y;
            acc[3][j] += w3.x * a.x + w3.y * a.y + w3.z * c.x + w3.w * c.y;
        }
    }
    if (!transpose) {
#pragma unroll
        for (int oo = 0; oo < 4; ++oo) {
            float* ob = out + ((size_t)b * CH + o0 + oo) * Lout + m0;
#pragma unroll
            for (int j = 0; j < 8; ++j)
                ob[mg + 8 * j] = fmaxf(acc[oo][j], 0.f);
        }
    } else {
#pragma unroll
        for (int j = 0; j < 8; ++j) {
            float* ob = out + ((size_t)b * Lout + m0 + mg + 8 * j) * CH + o0;
            float4 v;
            v.x = fmaxf(acc[0][j], 0.f);
            v.y = fmaxf(acc[1][j], 0.f);
            v.z = fmaxf(acc[2][j], 0.f);
            v.w = fmaxf(acc[3][j], 0.f);
            *(float4*)ob = v;
        }
    }
}

__global__ __launch_bounds__(128) void k_enc_conv(
    const float* __restrict__ in, const float* __restrict__ w,
    const float* __restrict__ bias, float* __restrict__ out,
    int Lin, int Lout, int transpose)
{
    __shared__ float lds[CH][132];
    const int m0 = blockIdx.x * 64;
    const int b = blockIdx.y;
    const int tid = threadIdx.x;
    const float* inb = in + (size_t)b * CH * Lin;
    const int g0 = 2 * m0 - 1;
    for (int e = tid; e < CH * 132; e += 128) {
        const int i = e / 132;
        const int pl = e - i * 132;
        const int p = g0 + pl;
        lds[i][pl] = (p >= 0 && p < Lin) ? inb[i * Lin + p] : 0.f;
    }
    __syncthreads();
    conv_core(lds, w, bias, out, b, m0, Lout, transpose, tid);
}

__global__ __launch_bounds__(128) void k_enc01(
    const float* __restrict__ x, const float* __restrict__ w0,
    const float* __restrict__ b0, const float* __restrict__ w1,
    const float* __restrict__ b1, float* __restrict__ out)
{
    __shared__ float xl[264];
    __shared__ float e0s[CH][132];
    const int m0 = blockIdx.x * 64;
    const int b = blockIdx.y;
    const int tid = threadIdx.x;
    const float* xb = x + (size_t)b * 65536;
    const int q0 = 4 * m0 - 3;
    for (int xi = tid; xi < 264; xi += 128) {
        const int q = q0 + xi;
        xl[xi] = (q >= 0 && q < 65536) ? xb[q] : 0.f;
    }
    __syncthreads();
    {
        const int i = tid >> 1;
        const int half = tid & 1;
        const float4 wv = *(const float4*)(w0 + i * 4);
        const float bv = b0[i];
        const int pl0 = half * 65;
        const int pbase = 2 * m0 - 1;
        for (int k = 0; k < 65; ++k) {
            const int pl = pl0 + k;
            const int pe = pbase + pl;
            const float* xp = xl + 2 * pl;
            const float v = wv.x * xp[0] + wv.y * xp[1] + wv.z * xp[2] + wv.w * xp[3] + bv;
            e0s[i][pl] = (pe >= 0 && pe < 32768) ? fmaxf(v, 0.f) : 0.f;
        }
    }
    __syncthreads();
    conv_core(e0s, w1, b1, out, b, m0, 16384, 0, tid);
}

// =====================================================================
// VQ (fp32, unchanged)
// =====================================================================
__global__ __launch_bounds__(256) void k_vq(
    const float* __restrict__ z, const float* __restrict__ cb,
    float* __restrict__ idsf, float* __restrict__ g)
{
    __shared__ float zl[64][68];
    __shared__ float cl[64][68];
    __shared__ float c2l[64];
    __shared__ float rval[64][16];
    __shared__ int ridx[64][16];
    __shared__ int widx[64];
    const int t0 = blockIdx.x * 64;
    const int tid = threadIdx.x;
    for (int e = tid; e < 64 * 64; e += 256) {
        const int tok = e >> 6, d = e & 63;
        zl[tok][d] = z[(size_t)(t0 + tok) * 64 + d];
    }
    const int tg = tid >> 4, cg = tid & 15;
    float best[4];
    int bidx[4];
#pragma unroll
    for (int tt = 0; tt < 4; ++tt) { best[tt] = 3.0e38f; bidx[tt] = 0; }
    for (int chk = 0; chk < 16; ++chk) {
        __syncthreads();
        for (int e = tid; e < 64 * 64; e += 256) {
            const int c = e >> 6, d = e & 63;
            cl[c][d] = cb[(size_t)(chk * 64 + c) * 64 + d];
        }
        __syncthreads();
        if (tid < 64) {
            float s = 0.f;
            for (int d = 0; d < 64; ++d) { const float v = cl[tid][d]; s += v * v; }
            c2l[tid] = s;
        }
        __syncthreads();
        float acc[4][4];
#pragma unroll
        for (int a = 0; a < 4; ++a)
#pragma unroll
            for (int c = 0; c < 4; ++c) acc[a][c] = 0.f;
        for (int d4 = 0; d4 < 16; ++d4) {
            float4 zv[4], cv[4];
#pragma unroll
            for (int tt = 0; tt < 4; ++tt) zv[tt] = *(const float4*)&zl[tg * 4 + tt][d4 * 4];
#pragma unroll
            for (int cc = 0; cc < 4; ++cc) cv[cc] = *(const float4*)&cl[cg * 4 + cc][d4 * 4];
#pragma unroll
            for (int tt = 0; tt < 4; ++tt)
#pragma unroll
                for (int cc = 0; cc < 4; ++cc)
                    acc[tt][cc] += zv[tt].x * cv[cc].x + zv[tt].y * cv[cc].y
                                 + zv[tt].z * cv[cc].z + zv[tt].w * cv[cc].w;
        }
#pragma unroll
        for (int cc = 0; cc < 4; ++cc) {
            const int code = chk * 64 + cg * 4 + cc;
            const float c2v = c2l[cg * 4 + cc];
#pragma unroll
            for (int tt = 0; tt < 4; ++tt) {
                const float s = c2v - 2.f * acc[tt][cc];
                if (s < best[tt]) { best[tt] = s; bidx[tt] = code; }
            }
        }
    }
#pragma unroll
    for (int tt = 0; tt < 4; ++tt) {
        rval[tg * 4 + tt][cg] = best[tt];
        ridx[tg * 4 + tt][cg] = bidx[tt];
    }
    __syncthreads();
    if (tid < 64) {
        float bv = rval[tid][0];
        int bi = ridx[tid][0];
        for (int k = 1; k < 16; ++k) {
            const float v = rval[tid][k];
            const int ix = ridx[tid][k];
            if (v < bv || (v == bv && ix < bi)) { bv = v; bi = ix; }
        }
        widx[tid] = bi;
        idsf[t0 + tid] = (float)bi;
    }
    __syncthreads();
    const int bb = t0 >> 10;
    const int mb = t0 & 1023;
    for (int e = tid; e < 64 * 64; e += 256) {
        const int tok = e & 63;
        const int d = e >> 6;
        g[((size_t)bb * CH + d) * 1024 + mb + tok] = cb[(size_t)widx[tok] * 64 + d];
    }
}

// =====================================================================
// DECODER: bf16 MFMA convT.
// Y[o,2u]   = b[o] + sum_i w[i,o,1]X[i,u] + w[i,o,3]X[i,u-1]   (phase E)
// Y[o,2u+1] = b[o] + sum_i w[i,o,2]X[i,u] + w[i,o,0]X[i,u+1]   (phase O)
// GEMM per phase: A[64 o][128 k] (k=2i+t), B[128 k][u], K=128.
// mfma_f32_16x16x32_bf16: A row=l&15, k=(l>>4)*8+j; B col=l&15, same k;
// D row=(l>>4)*4+r, col=l&15.
// =====================================================================

// Prepack dec_w (5,64,64,4) fp32 -> fragment-linear bf16 [L][p][m][kt][lane][j]
__global__ __launch_bounds__(256) void k_prepack(
    const float* __restrict__ dec_w, ushort* __restrict__ Afrag)
{
    const int idx = blockIdx.x * 256 + threadIdx.x;   // 5*16384 = 81920 total
    const int j    = idx & 7;
    const int lane = (idx >> 3) & 63;
    const int kt   = (idx >> 9) & 3;
    const int m    = (idx >> 11) & 3;
    const int p    = (idx >> 13) & 1;
    const int L    = idx >> 14;
    const int o = m * 16 + (lane & 15);
    const int k = kt * 32 + (lane >> 4) * 8 + j;
    const int i = k >> 1;
    const int t = k & 1;
    const int tau = p ? (t ? 0 : 2) : (t ? 3 : 1);
    const float v = dec_w[(((size_t)L * 64 + i) * 64 + o) * 4 + tau];
    Afrag[idx] = f2bf(v);
}

// One convT layer. Block: 64 u-columns, 256 threads (4 waves).
__global__ __launch_bounds__(256) void k_dec_mfma(
    const float* __restrict__ X, const ushort* __restrict__ Afrag,
    const float* __restrict__ bias, float* __restrict__ Y, int Lin)
{
    __shared__ __align__(16) ushort BE[64 * 136];
    __shared__ __align__(16) ushort BO[64 * 136];
    const int u0 = blockIdx.x * 64;
    const int b  = blockIdx.y;
    const int tid = threadIdx.x;
    const int Lout = Lin * 2;

    // ---- stage B (bf16 pairs, k-contiguous) ----
    uint* BEw = (uint*)BE;
    uint* BOw = (uint*)BO;
#pragma unroll
    for (int s = 0; s < 4; ++s) {
        const int e = tid + 256 * s;          // 1024 tasks: (ml, i4)
        const int ml = e & 63;
        const int i4 = (e >> 6) * 4;
        const int u = u0 + ml;
        const float* xc = X + ((size_t)b * 64 + i4) * Lin + u;
        uint eD[4], oD[4];
#pragma unroll
        for (int r = 0; r < 4; ++r) {
            const float* xr = xc + (size_t)r * Lin;
            const float x0 = xr[0];
            const float xm = (u > 0) ? xr[-1] : 0.f;
            const float xp = (u + 1 < Lin) ? xr[1] : 0.f;
            const uint b0 = f2bf(x0);
            eD[r] = b0 | ((uint)f2bf(xm) << 16);
            oD[r] = b0 | ((uint)f2bf(xp) << 16);
        }
        *(uint4*)&BEw[ml * 68 + i4] = make_uint4(eD[0], eD[1], eD[2], eD[3]);
        *(uint4*)&BOw[ml * 68 + i4] = make_uint4(oD[0], oD[1], oD[2], oD[3]);
    }
    __syncthreads();

    // ---- MFMA ----
    const int wave = tid >> 6, lane = tid & 63;
    const int col = lane & 15, kg = lane >> 4;
    const int ml = wave * 16 + col;
    const s16x8* BEf = (const s16x8*)&BE[ml * 136 + kg * 8];
    const s16x8* BOf = (const s16x8*)&BO[ml * 136 + kg * 8];
    s16x8 be[4], bo[4];
#pragma unroll
    for (int kt = 0; kt < 4; ++kt) { be[kt] = BEf[4 * kt]; bo[kt] = BOf[4 * kt]; }

    const s16x8* Af = (const s16x8*)Afrag;
    const int n2 = 2 * (u0 + ml);
#pragma unroll
    for (int m = 0; m < 4; ++m) {
        const s16x8* Ae = Af + ((0 * 4 + m) * 4) * 64 + lane;
        const s16x8* Ao = Af + ((1 * 4 + m) * 4) * 64 + lane;
        f32x4 accE = {0.f, 0.f, 0.f, 0.f};
        f32x4 accO = {0.f, 0.f, 0.f, 0.f};
#pragma unroll
        for (int kt = 0; kt < 4; ++kt) {
            accE = __builtin_amdgcn_mfma_f32_16x16x32_bf16(Ae[kt * 64], be[kt], accE, 0, 0, 0);
            accO = __builtin_amdgcn_mfma_f32_16x16x32_bf16(Ao[kt * 64], bo[kt], accO, 0, 0, 0);
        }
        const float4 bm4 = *(const float4*)(bias + m * 16 + kg * 4);
        float* yo = Y + ((size_t)b * 64 + m * 16 + kg * 4) * Lout + n2;
        const float bb[4] = {bm4.x, bm4.y, bm4.z, bm4.w};
#pragma unroll
        for (int r = 0; r < 4; ++r) {
            float2 v;
            v.x = fmaxf(accE[r] + bb[r], 0.f);
            v.y = fmaxf(accO[r] + bb[r], 0.f);
            *(float2*)(yo + (size_t)r * Lout) = v;
        }
    }
}

// Last convT (64 -> 1, no relu), fp32, d4 quarter in global.
__global__ __launch_bounds__(256) void k_last(
    const float* __restrict__ d4, const float* __restrict__ wl,
    const float* __restrict__ blp, float* __restrict__ y, int bbase)
{
    __shared__ float dl[64][260];
    const int n0 = blockIdx.x * 512;      // 512 y outputs per block
    const int bl = blockIdx.y;            // local batch 0..3
    const int v0 = n0 >> 1;
    const int tid = threadIdx.x;
    const float* db = d4 + (size_t)bl * 64 * 32768;
    for (int e = tid; e < 64 * 258; e += 256) {
        const int i = e / 258;
        const int pl = e - i * 258;
        const int v = v0 - 1 + pl;
        dl[i][pl] = (v >= 0 && v < 32768) ? db[(size_t)i * 32768 + v] : 0.f;
    }
    __syncthreads();
    const int pl = tid + 1;               // dl index of v = v0 + tid
    float accE = blp[0], accO = blp[0];
    for (int i = 0; i < 64; ++i) {
        const float4 wv = *(const float4*)(wl + i * 4);
        const float xm = dl[i][pl - 1];
        const float x0 = dl[i][pl];
        const float xp = dl[i][pl + 1];
        accE += wv.y * x0 + wv.w * xm;
        accO += wv.z * x0 + wv.x * xp;
    }
    float* yb = y + (size_t)(bbase + bl) * 65536 + n0 + 2 * tid;
    yb[0] = accE;
    yb[1] = accO;
}

extern "C" void kernel_launch(void* const* d_in, const int* in_sizes, int n_in,
                              void* d_out, int out_size, void* d_ws, size_t ws_size,
                              hipStream_t stream) {
    const float* x      = (const float*)d_in[0];
    const float* enc_w0 = (const float*)d_in[1];
    const float* enc_w  = (const float*)d_in[2];   // (5,64,64,4)
    const float* enc_b  = (const float*)d_in[3];   // (6,64)
    const float* cb     = (const float*)d_in[4];   // (1024,64)
    const float* dec_w  = (const float*)d_in[5];   // (5,64,64,4) [in][out][k]
    const float* dec_wl = (const float*)d_in[6];   // (64,1,4)
    const float* dec_b  = (const float*)d_in[7];   // (5,64)
    const float* dec_bl = (const float*)d_in[8];   // (1,)
    float* y    = (float*)d_out;                   // (16,1,65536)
    float* z_e  = y + 1048576;                     // (16384,64)
    float* idsf = y + 2097152;                     // (16384,)

    // workspace overlay: A = 16.7M floats (67MB), Bf = 8.4M floats (33.6MB)
    float* A  = (float*)d_ws;
    float* Bf = A + 16777216;

    // Prepacked decoder A-fragments (5 layers x 16384 ushort = 160KB) live in
    // the tail of y's batch-15 region: dead until the FINAL k_last (q=3)
    // overwrites it, which runs after the last use (dec4 q=3). Avoids
    // assuming ws_size > 100.7MB.
    ushort* Afrag = (ushort*)(y + 1048576 - 40960);

    const int WSTRIDE = 64 * 64 * 4;

    k_prepack<<<dim3(320), 256, 0, stream>>>(dec_w, Afrag);

    // encoder (fp32)
    k_enc01<<<dim3(256, 16), 128, 0, stream>>>(x, enc_w0, enc_b, enc_w, enc_b + 64, A);
    k_enc_conv<<<dim3(128, 16), 128, 0, stream>>>(A,  enc_w + 1 * WSTRIDE, enc_b + 2 * 64, Bf, 16384, 8192, 0);
    k_enc_conv<<<dim3(64, 16),  128, 0, stream>>>(Bf, enc_w + 2 * WSTRIDE, enc_b + 3 * 64, A,  8192,  4096, 0);
    k_enc_conv<<<dim3(32, 16),  128, 0, stream>>>(A,  enc_w + 3 * WSTRIDE, enc_b + 4 * 64, Bf, 4096,  2048, 0);
    k_enc_conv<<<dim3(16, 16),  128, 0, stream>>>(Bf, enc_w + 4 * WSTRIDE, enc_b + 5 * 64, z_e, 2048, 1024, 1);
    // vector quantize (fp32) -> g in A
    k_vq<<<256, 256, 0, stream>>>(z_e, cb, idsf, A);

    // decoder (bf16 MFMA): g(A,1024) -> d0(Bf) -> d1(A) -> d2(Bf) -> d3(A)
    k_dec_mfma<<<dim3(16, 16),  256, 0, stream>>>(A,  Afrag + 0 * 16384, dec_b + 0 * 64, Bf, 1024);
    k_dec_mfma<<<dim3(32, 16),  256, 0, stream>>>(Bf, Afrag + 1 * 16384, dec_b + 1 * 64, A,  2048);
    k_dec_mfma<<<dim3(64, 16),  256, 0, stream>>>(A,  Afrag + 2 * 16384, dec_b + 2 * 64, Bf, 4096);
    k_dec_mfma<<<dim3(128, 16), 256, 0, stream>>>(Bf, Afrag + 3 * 16384, dec_b + 3 * 64, A,  8192);
    // dec4 + last in 4-batch quarters through Bf (d4 doesn't fit ws whole)
    for (int q = 0; q < 4; ++q) {
        k_dec_mfma<<<dim3(256, 4), 256, 0, stream>>>(A + (size_t)q * 4 * 64 * 16384,
                                                     Afrag + 4 * 16384, dec_b + 4 * 64, Bf, 16384);
        k_last<<<dim3(128, 4), 256, 0, stream>>>(Bf, dec_wl, dec_bl, y, q * 4);
    }
}

// Round 5
// 683.036 us; speedup vs baseline: 1.7476x; 1.2461x over previous
//
#include <hip/hip_runtime.h>

#define CH 64
#define TILE 128

typedef short s16x8 __attribute__((ext_vector_type(8)));
typedef float f32x4 __attribute__((ext_vector_type(4)));

static __device__ __forceinline__ ushort f2bf(float f) {
    union { float f; uint u; } v; v.f = f;
    const uint r = (v.u + 0x7FFFu + ((v.u >> 16) & 1u)) >> 16;
    return (ushort)r;
}

// =====================================================================
// ENCODER (fp32): 128-pos tile, 256 threads, K processed in two
// 32-channel halves staged in LDS (34KB -> 4 blocks/CU).
// Thread: o0 = (tid>>4)*4 out-ch, pg = tid&15 -> positions
// ml = 4*pg + 64*c + q  (c=0,1 chunks; q=0..3 consecutive).
// lds row holds input p = 2*m0 - 1 + pl, pl in [0,258).
// =====================================================================

// stage rows [half*32, half*32+32) of the input tile into inT
__device__ __forceinline__ void stage_half(
    const float* __restrict__ inb, float (*inT)[260], int half,
    int m0, int Lin, int tid)
{
    const int r = tid >> 3;            // 0..31
    const int i = half * 32 + r;
    const int seg = tid & 7;
    // interior pl = 1 + 32*seg + 4t : p = 2*m0 + 32*seg + 4t, always in bounds
    const float* src = inb + (size_t)i * Lin + 2 * m0 + 32 * seg;
    float* dst = inT[r] + 1 + 32 * seg;
#pragma unroll
    for (int t = 0; t < 8; ++t) {
        const float4 v = *(const float4*)(src + 4 * t);
        float* d = dst + 4 * t;
        d[0] = v.x;
        *(float2*)(d + 1) = make_float2(v.y, v.z);
        d[3] = v.w;
    }
    if (tid < 64) {                    // edges pl=0 and pl=257
        const int rr = tid & 31, side = tid >> 5;
        const int pl = side ? 257 : 0;
        const int p = 2 * m0 - 1 + pl;
        inT[rr][pl] = (p >= 0 && p < Lin) ? inb[(size_t)(half * 32 + rr) * Lin + p] : 0.f;
    }
}

// accumulate 32 input channels (weights at i = ibase+ii)
__device__ __forceinline__ void conv_accum_half(
    const float (*inT)[260], const float* __restrict__ w, int ibase,
    float acc[4][8], int o0, int pg)
{
    for (int ii = 0; ii < 32; ++ii) {
        const int i = ibase + ii;
        const float4 w0 = *(const float4*)(w + ((o0 + 0) * CH + i) * 4);
        const float4 w1 = *(const float4*)(w + ((o0 + 1) * CH + i) * 4);
        const float4 w2 = *(const float4*)(w + ((o0 + 2) * CH + i) * 4);
        const float4 w3 = *(const float4*)(w + ((o0 + 3) * CH + i) * 4);
        const float* row = inT[ii];
#pragma unroll
        for (int c = 0; c < 2; ++c) {
            const int pl0 = 8 * pg + 128 * c;
            const float4 xa = *(const float4*)(row + pl0);
            const float4 xb = *(const float4*)(row + pl0 + 4);
            const float2 xc = *(const float2*)(row + pl0 + 8);
            const float xv[10] = {xa.x, xa.y, xa.z, xa.w, xb.x, xb.y, xb.z, xb.w, xc.x, xc.y};
#pragma unroll
            for (int q = 0; q < 4; ++q) {
                const int j = 4 * c + q;
                acc[0][j] += w0.x * xv[2*q] + w0.y * xv[2*q+1] + w0.z * xv[2*q+2] + w0.w * xv[2*q+3];
                acc[1][j] += w1.x * xv[2*q] + w1.y * xv[2*q+1] + w1.z * xv[2*q+2] + w1.w * xv[2*q+3];
                acc[2][j] += w2.x * xv[2*q] + w2.y * xv[2*q+1] + w2.z * xv[2*q+2] + w2.w * xv[2*q+3];
                acc[3][j] += w3.x * xv[2*q] + w3.y * xv[2*q+1] + w3.z * xv[2*q+2] + w3.w * xv[2*q+3];
            }
        }
    }
}

__device__ __forceinline__ void conv_epilogue(
    float acc[4][8], const float* __restrict__ bias, float* __restrict__ out,
    int b, int m0, int Lout, int transpose, int o0, int pg)
{
    if (!transpose) {
#pragma unroll
        for (int oo = 0; oo < 4; ++oo) {
            float* ob = out + ((size_t)b * CH + o0 + oo) * Lout + m0;
#pragma unroll
            for (int c = 0; c < 2; ++c) {
                float4 v;
                v.x = fmaxf(acc[oo][4*c+0], 0.f);
                v.y = fmaxf(acc[oo][4*c+1], 0.f);
                v.z = fmaxf(acc[oo][4*c+2], 0.f);
                v.w = fmaxf(acc[oo][4*c+3], 0.f);
                *(float4*)(ob + 4 * pg + 64 * c) = v;
            }
        }
    } else {
#pragma unroll
        for (int c = 0; c < 2; ++c)
#pragma unroll
            for (int q = 0; q < 4; ++q) {
                const int ml = 4 * pg + 64 * c + q;
                float* ob = out + ((size_t)b * Lout + m0 + ml) * CH + o0;
                float4 v;
                v.x = fmaxf(acc[0][4*c+q], 0.f);
                v.y = fmaxf(acc[1][4*c+q], 0.f);
                v.z = fmaxf(acc[2][4*c+q], 0.f);
                v.w = fmaxf(acc[3][4*c+q], 0.f);
                *(float4*)ob = v;
            }
    }
}

__global__ __launch_bounds__(256) void k_enc_conv(
    const float* __restrict__ in, const float* __restrict__ w,
    const float* __restrict__ bias, float* __restrict__ out,
    int Lin, int Lout, int transpose)
{
    __shared__ float inT[32][260];
    const int m0 = blockIdx.x * TILE;
    const int b = blockIdx.y;
    const int tid = threadIdx.x;
    const float* inb = in + (size_t)b * CH * Lin;
    const int o0 = (tid >> 4) * 4;
    const int pg = tid & 15;
    float acc[4][8];
#pragma unroll
    for (int oo = 0; oo < 4; ++oo) {
        const float bv = bias[o0 + oo];
#pragma unroll
        for (int j = 0; j < 8; ++j) acc[oo][j] = bv;
    }
    stage_half(inb, inT, 0, m0, Lin, tid);
    __syncthreads();
    conv_accum_half(inT, w, 0, acc, o0, pg);
    __syncthreads();
    stage_half(inb, inT, 1, m0, Lin, tid);
    __syncthreads();
    conv_accum_half(inT, w, 32, acc, o0, pg);
    conv_epilogue(acc, bias, out, b, m0, Lout, transpose, o0, pg);
}

// fused conv0 (1->64) + conv1 (64->64); e0 channels computed in two halves
__global__ __launch_bounds__(256) void k_enc01(
    const float* __restrict__ x, const float* __restrict__ w0,
    const float* __restrict__ b0, const float* __restrict__ w1,
    const float* __restrict__ b1, float* __restrict__ out)
{
    __shared__ float xl[520];
    __shared__ float e0s[32][260];
    const int m0 = blockIdx.x * TILE;
    const int b = blockIdx.y;
    const int tid = threadIdx.x;
    const float* xb = x + (size_t)b * 65536;
    const int x0i = 4 * m0 - 3;
    for (int xi = tid; xi < 518; xi += 256) {
        const int q = x0i + xi;
        xl[xi] = (q >= 0 && q < 65536) ? xb[q] : 0.f;
    }
    const int o0 = (tid >> 4) * 4;
    const int pg = tid & 15;
    float acc[4][8];
#pragma unroll
    for (int oo = 0; oo < 4; ++oo) {
        const float bv = b1[o0 + oo];
#pragma unroll
        for (int j = 0; j < 8; ++j) acc[oo][j] = bv;
    }
    const int r = tid >> 3;            // e0 row worker: 0..31
    const int oct = tid & 7;
    const int pbase = 2 * m0 - 1;      // e0-pos of pl=0; e0 length = 32768
    __syncthreads();
#pragma unroll
    for (int half = 0; half < 2; ++half) {
        {
            const int i = half * 32 + r;
            const float4 wv = *(const float4*)(w0 + i * 4);
            const float bv = b0[i];
            for (int t = 0; t < 33; ++t) {
                const int pl = oct * 33 + t;
                if (pl < 258) {
                    const int pe = pbase + pl;
                    const float* xp = xl + 2 * pl;
                    const float v = wv.x * xp[0] + wv.y * xp[1] + wv.z * xp[2] + wv.w * xp[3] + bv;
                    e0s[r][pl] = (pe >= 0 && pe < 32768) ? fmaxf(v, 0.f) : 0.f;
                }
            }
        }
        __syncthreads();
        conv_accum_half(e0s, w1, half * 32, acc, o0, pg);
        __syncthreads();
    }
    conv_epilogue(acc, b1, out, b, m0, 16384, 0, o0, pg);
}

// =====================================================================
// VQ (fp32, unchanged)
// =====================================================================
__global__ __launch_bounds__(256) void k_vq(
    const float* __restrict__ z, const float* __restrict__ cb,
    float* __restrict__ idsf, float* __restrict__ g)
{
    __shared__ float zl[64][68];
    __shared__ float cl[64][68];
    __shared__ float c2l[64];
    __shared__ float rval[64][16];
    __shared__ int ridx[64][16];
    __shared__ int widx[64];
    const int t0 = blockIdx.x * 64;
    const int tid = threadIdx.x;
    for (int e = tid; e < 64 * 64; e += 256) {
        const int tok = e >> 6, d = e & 63;
        zl[tok][d] = z[(size_t)(t0 + tok) * 64 + d];
    }
    const int tg = tid >> 4, cg = tid & 15;
    float best[4];
    int bidx[4];
#pragma unroll
    for (int tt = 0; tt < 4; ++tt) { best[tt] = 3.0e38f; bidx[tt] = 0; }
    for (int chk = 0; chk < 16; ++chk) {
        __syncthreads();
        for (int e = tid; e < 64 * 64; e += 256) {
            const int c = e >> 6, d = e & 63;
            cl[c][d] = cb[(size_t)(chk * 64 + c) * 64 + d];
        }
        __syncthreads();
        if (tid < 64) {
            float s = 0.f;
            for (int d = 0; d < 64; ++d) { const float v = cl[tid][d]; s += v * v; }
            c2l[tid] = s;
        }
        __syncthreads();
        float acc[4][4];
#pragma unroll
        for (int a = 0; a < 4; ++a)
#pragma unroll
            for (int c = 0; c < 4; ++c) acc[a][c] = 0.f;
        for (int d4 = 0; d4 < 16; ++d4) {
            float4 zv[4], cv[4];
#pragma unroll
            for (int tt = 0; tt < 4; ++tt) zv[tt] = *(const float4*)&zl[tg * 4 + tt][d4 * 4];
#pragma unroll
            for (int cc = 0; cc < 4; ++cc) cv[cc] = *(const float4*)&cl[cg * 4 + cc][d4 * 4];
#pragma unroll
            for (int tt = 0; tt < 4; ++tt)
#pragma unroll
                for (int cc = 0; cc < 4; ++cc)
                    acc[tt][cc] += zv[tt].x * cv[cc].x + zv[tt].y * cv[cc].y
                                 + zv[tt].z * cv[cc].z + zv[tt].w * cv[cc].w;
        }
#pragma unroll
        for (int cc = 0; cc < 4; ++cc) {
            const int code = chk * 64 + cg * 4 + cc;
            const float c2v = c2l[cg * 4 + cc];
#pragma unroll
            for (int tt = 0; tt < 4; ++tt) {
                const float s = c2v - 2.f * acc[tt][cc];
                if (s < best[tt]) { best[tt] = s; bidx[tt] = code; }
            }
        }
    }
#pragma unroll
    for (int tt = 0; tt < 4; ++tt) {
        rval[tg * 4 + tt][cg] = best[tt];
        ridx[tg * 4 + tt][cg] = bidx[tt];
    }
    __syncthreads();
    if (tid < 64) {
        float bv = rval[tid][0];
        int bi = ridx[tid][0];
        for (int k = 1; k < 16; ++k) {
            const float v = rval[tid][k];
            const int ix = ridx[tid][k];
            if (v < bv || (v == bv && ix < bi)) { bv = v; bi = ix; }
        }
        widx[tid] = bi;
        idsf[t0 + tid] = (float)bi;
    }
    __syncthreads();
    const int bb = t0 >> 10;
    const int mb = t0 & 1023;
    for (int e = tid; e < 64 * 64; e += 256) {
        const int tok = e & 63;
        const int d = e >> 6;
        g[((size_t)bb * CH + d) * 1024 + mb + tok] = cb[(size_t)widx[tok] * 64 + d];
    }
}

// =====================================================================
// DECODER: bf16 MFMA convT (unchanged from round 4)
// =====================================================================
__global__ __launch_bounds__(256) void k_prepack(
    const float* __restrict__ dec_w, ushort* __restrict__ Afrag)
{
    const int idx = blockIdx.x * 256 + threadIdx.x;   // 5*16384 = 81920 total
    const int j    = idx & 7;
    const int lane = (idx >> 3) & 63;
    const int kt   = (idx >> 9) & 3;
    const int m    = (idx >> 11) & 3;
    const int p    = (idx >> 13) & 1;
    const int L    = idx >> 14;
    const int o = m * 16 + (lane & 15);
    const int k = kt * 32 + (lane >> 4) * 8 + j;
    const int i = k >> 1;
    const int t = k & 1;
    const int tau = p ? (t ? 0 : 2) : (t ? 3 : 1);
    const float v = dec_w[(((size_t)L * 64 + i) * 64 + o) * 4 + tau];
    Afrag[idx] = f2bf(v);
}

__global__ __launch_bounds__(256) void k_dec_mfma(
    const float* __restrict__ X, const ushort* __restrict__ Afrag,
    const float* __restrict__ bias, float* __restrict__ Y, int Lin)
{
    __shared__ __align__(16) ushort BE[64 * 136];
    __shared__ __align__(16) ushort BO[64 * 136];
    const int u0 = blockIdx.x * 64;
    const int b  = blockIdx.y;
    const int tid = threadIdx.x;
    const int Lout = Lin * 2;

    uint* BEw = (uint*)BE;
    uint* BOw = (uint*)BO;
#pragma unroll
    for (int s = 0; s < 4; ++s) {
        const int e = tid + 256 * s;          // 1024 tasks: (ml, i4)
        const int ml = e & 63;
        const int i4 = (e >> 6) * 4;
        const int u = u0 + ml;
        const float* xc = X + ((size_t)b * 64 + i4) * Lin + u;
        uint eD[4], oD[4];
#pragma unroll
        for (int r = 0; r < 4; ++r) {
            const float* xr = xc + (size_t)r * Lin;
            const float x0 = xr[0];
            const float xm = (u > 0) ? xr[-1] : 0.f;
            const float xp = (u + 1 < Lin) ? xr[1] : 0.f;
            const uint b0 = f2bf(x0);
            eD[r] = b0 | ((uint)f2bf(xm) << 16);
            oD[r] = b0 | ((uint)f2bf(xp) << 16);
        }
        *(uint4*)&BEw[ml * 68 + i4] = make_uint4(eD[0], eD[1], eD[2], eD[3]);
        *(uint4*)&BOw[ml * 68 + i4] = make_uint4(oD[0], oD[1], oD[2], oD[3]);
    }
    __syncthreads();

    const int wave = tid >> 6, lane = tid & 63;
    const int col = lane & 15, kg = lane >> 4;
    const int ml = wave * 16 + col;
    const s16x8* BEf = (const s16x8*)&BE[ml * 136 + kg * 8];
    const s16x8* BOf = (const s16x8*)&BO[ml * 136 + kg * 8];
    s16x8 be[4], bo[4];
#pragma unroll
    for (int kt = 0; kt < 4; ++kt) { be[kt] = BEf[4 * kt]; bo[kt] = BOf[4 * kt]; }

    const s16x8* Af = (const s16x8*)Afrag;
    const int n2 = 2 * (u0 + ml);
#pragma unroll
    for (int m = 0; m < 4; ++m) {
        const s16x8* Ae = Af + ((0 * 4 + m) * 4) * 64 + lane;
        const s16x8* Ao = Af + ((1 * 4 + m) * 4) * 64 + lane;
        f32x4 accE = {0.f, 0.f, 0.f, 0.f};
        f32x4 accO = {0.f, 0.f, 0.f, 0.f};
#pragma unroll
        for (int kt = 0; kt < 4; ++kt) {
            accE = __builtin_amdgcn_mfma_f32_16x16x32_bf16(Ae[kt * 64], be[kt], accE, 0, 0, 0);
            accO = __builtin_amdgcn_mfma_f32_16x16x32_bf16(Ao[kt * 64], bo[kt], accO, 0, 0, 0);
        }
        const float4 bm4 = *(const float4*)(bias + m * 16 + kg * 4);
        float* yo = Y + ((size_t)b * 64 + m * 16 + kg * 4) * Lout + n2;
        const float bb[4] = {bm4.x, bm4.y, bm4.z, bm4.w};
#pragma unroll
        for (int r = 0; r < 4; ++r) {
            float2 v;
            v.x = fmaxf(accE[r] + bb[r], 0.f);
            v.y = fmaxf(accO[r] + bb[r], 0.f);
            *(float2*)(yo + (size_t)r * Lout) = v;
        }
    }
}

__global__ __launch_bounds__(256) void k_last(
    const float* __restrict__ d4, const float* __restrict__ wl,
    const float* __restrict__ blp, float* __restrict__ y, int bbase)
{
    __shared__ float dl[64][260];
    const int n0 = blockIdx.x * 512;      // 512 y outputs per block
    const int bl = blockIdx.y;            // local batch 0..3
    const int v0 = n0 >> 1;
    const int tid = threadIdx.x;
    const float* db = d4 + (size_t)bl * 64 * 32768;
    for (int e = tid; e < 64 * 258; e += 256) {
        const int i = e / 258;
        const int pl = e - i * 258;
        const int v = v0 - 1 + pl;
        dl[i][pl] = (v >= 0 && v < 32768) ? db[(size_t)i * 32768 + v] : 0.f;
    }
    __syncthreads();
    const int pl = tid + 1;               // dl index of v = v0 + tid
    float accE = blp[0], accO = blp[0];
    for (int i = 0; i < 64; ++i) {
        const float4 wv = *(const float4*)(wl + i * 4);
        const float xm = dl[i][pl - 1];
        const float x0 = dl[i][pl];
        const float xp = dl[i][pl + 1];
        accE += wv.y * x0 + wv.w * xm;
        accO += wv.z * x0 + wv.x * xp;
    }
    float* yb = y + (size_t)(bbase + bl) * 65536 + n0 + 2 * tid;
    yb[0] = accE;
    yb[1] = accO;
}

extern "C" void kernel_launch(void* const* d_in, const int* in_sizes, int n_in,
                              void* d_out, int out_size, void* d_ws, size_t ws_size,
                              hipStream_t stream) {
    const float* x      = (const float*)d_in[0];
    const float* enc_w0 = (const float*)d_in[1];
    const float* enc_w  = (const float*)d_in[2];   // (5,64,64,4)
    const float* enc_b  = (const float*)d_in[3];   // (6,64)
    const float* cb     = (const float*)d_in[4];   // (1024,64)
    const float* dec_w  = (const float*)d_in[5];   // (5,64,64,4) [in][out][k]
    const float* dec_wl = (const float*)d_in[6];   // (64,1,4)
    const float* dec_b  = (const float*)d_in[7];   // (5,64)
    const float* dec_bl = (const float*)d_in[8];   // (1,)
    float* y    = (float*)d_out;                   // (16,1,65536)
    float* z_e  = y + 1048576;                     // (16384,64)
    float* idsf = y + 2097152;                     // (16384,)

    // workspace overlay: A = 16.7M floats (67MB), Bf = 8.4M floats (33.6MB)
    float* A  = (float*)d_ws;
    float* Bf = A + 16777216;

    // Prepacked decoder A-fragments (160KB) in tail of y's batch-15 region:
    // dead until the FINAL k_last (q=3) overwrites it.
    ushort* Afrag = (ushort*)(y + 1048576 - 40960);

    const int WSTRIDE = 64 * 64 * 4;

    k_prepack<<<dim3(320), 256, 0, stream>>>(dec_w, Afrag);

    // encoder (fp32, 128-pos tiles)
    k_enc01<<<dim3(128, 16), 256, 0, stream>>>(x, enc_w0, enc_b, enc_w, enc_b + 64, A);
    k_enc_conv<<<dim3(64, 16), 256, 0, stream>>>(A,  enc_w + 1 * WSTRIDE, enc_b + 2 * 64, Bf, 16384, 8192, 0);
    k_enc_conv<<<dim3(32, 16), 256, 0, stream>>>(Bf, enc_w + 2 * WSTRIDE, enc_b + 3 * 64, A,  8192,  4096, 0);
    k_enc_conv<<<dim3(16, 16), 256, 0, stream>>>(A,  enc_w + 3 * WSTRIDE, enc_b + 4 * 64, Bf, 4096,  2048, 0);
    k_enc_conv<<<dim3(8, 16),  256, 0, stream>>>(Bf, enc_w + 4 * WSTRIDE, enc_b + 5 * 64, z_e, 2048, 1024, 1);
    // vector quantize (fp32) -> g in A
    k_vq<<<256, 256, 0, stream>>>(z_e, cb, idsf, A);

    // decoder (bf16 MFMA)
    k_dec_mfma<<<dim3(16, 16),  256, 0, stream>>>(A,  Afrag + 0 * 16384, dec_b + 0 * 64, Bf, 1024);
    k_dec_mfma<<<dim3(32, 16),  256, 0, stream>>>(Bf, Afrag + 1 * 16384, dec_b + 1 * 64, A,  2048);
    k_dec_mfma<<<dim3(64, 16),  256, 0, stream>>>(A,  Afrag + 2 * 16384, dec_b + 2 * 64, Bf, 4096);
    k_dec_mfma<<<dim3(128, 16), 256, 0, stream>>>(Bf, Afrag + 3 * 16384, dec_b + 3 * 64, A,  8192);
    for (int q = 0; q < 4; ++q) {
        k_dec_mfma<<<dim3(256, 4), 256, 0, stream>>>(A + (size_t)q * 4 * 64 * 16384,
                                                     Afrag + 4 * 16384, dec_b + 4 * 64, Bf, 16384);
        k_last<<<dim3(128, 4), 256, 0, stream>>>(Bf, dec_wl, dec_bl, y, q * 4);
    }
}